// Round 1
// baseline (884.101 us; speedup 1.0000x reference)
//
#include <hip/hip_runtime.h>
#include <hip/hip_bf16.h>
#include <stdint.h>

// Problem sizes (fixed by the reference)
#define IN_F  4096
#define OUT_F 4096
#define NROWS 16384

// GEMM tile config (m97-style: 128x128 tile, BK=64, 4 waves of 64x64)
#define BM 128
#define BN 128
#define BK 64

typedef unsigned short u16;
typedef __bf16 bf16x8 __attribute__((ext_vector_type(8)));
typedef float  f32x4  __attribute__((ext_vector_type(4)));
typedef u16    u16x8  __attribute__((ext_vector_type(8)));

// fp32 -> bf16, round-to-nearest-even (finite inputs only)
__device__ __forceinline__ u16 f2bf(float x) {
    union { float f; uint32_t u; } c; c.f = x;
    uint32_t u = c.u;
    return (u16)((u + 0x7FFFu + ((u >> 16) & 1u)) >> 16);
}

// async global->LDS, 16B per lane. LDS dest must be wave-uniform base + lane*16.
__device__ __forceinline__ void gload_lds16(const void* g, void* l) {
    __builtin_amdgcn_global_load_lds(
        (const __attribute__((address_space(1))) void*)g,
        (__attribute__((address_space(3))) void*)l, 16, 0, 0);
}

// --- Prep 1: per-row alpha = mean(|W|) AND binarized W as bf16 {+1,-1,0} ---
__global__ void prep_w_kernel(const float* __restrict__ W,
                              float* __restrict__ alpha,
                              u16* __restrict__ S) {
    const int row = blockIdx.x;                       // 0..OUT_F-1
    const float4* w4 = reinterpret_cast<const float4*>(W) + (size_t)row * (IN_F / 4);
    ushort4* s4 = reinterpret_cast<ushort4*>(S) + (size_t)row * (IN_F / 4);
    float s = 0.f;
    for (int i = threadIdx.x; i < IN_F / 4; i += 256) {
        float4 v = w4[i];
        s += fabsf(v.x) + fabsf(v.y) + fabsf(v.z) + fabsf(v.w);
        ushort4 r;
        r.x = v.x > 0.f ? 0x3F80 : (v.x < 0.f ? 0xBF80 : 0);
        r.y = v.y > 0.f ? 0x3F80 : (v.y < 0.f ? 0xBF80 : 0);
        r.z = v.z > 0.f ? 0x3F80 : (v.z < 0.f ? 0xBF80 : 0);
        r.w = v.w > 0.f ? 0x3F80 : (v.w < 0.f ? 0xBF80 : 0);
        s4[i] = r;
    }
    // wave reduce (wave64) then cross-wave via LDS
    for (int off = 32; off > 0; off >>= 1) s += __shfl_down(s, off);
    __shared__ float red[4];
    const int wave = threadIdx.x >> 6, lane = threadIdx.x & 63;
    if (lane == 0) red[wave] = s;
    __syncthreads();
    if (threadIdx.x == 0)
        alpha[row] = (red[0] + red[1] + red[2] + red[3]) * (1.0f / IN_F);
}

// --- Prep 2: x fp32 -> bf16 (RNE), 8 elems/thread ---
__global__ void convx_kernel(const float* __restrict__ X, u16* __restrict__ O) {
    const size_t idx = (size_t)blockIdx.x * 256 + threadIdx.x; // one 16B chunk each
    const float4* src = reinterpret_cast<const float4*>(X) + idx * 2;
    float4 a = src[0], b = src[1];
    u16x8 r;
    r[0] = f2bf(a.x); r[1] = f2bf(a.y); r[2] = f2bf(a.z); r[3] = f2bf(a.w);
    r[4] = f2bf(b.x); r[5] = f2bf(b.y); r[6] = f2bf(b.z); r[7] = f2bf(b.w);
    reinterpret_cast<u16x8*>(O)[idx] = r;
}

// --- GEMM: Y[m][n] = alpha[n] * sum_k Xbf[m][k]*S[n][k] + bias[n] ---
// A_FROM_F32=false: A staged from bf16 workspace via global_load_lds (fast path)
// A_FROM_F32=true : A reg-staged from fp32 X with fused f32->bf16 (small-ws path)
template <bool A_FROM_F32>
__global__ __launch_bounds__(256) void gemm_kernel(
    const float* __restrict__ X, const u16* __restrict__ Xbf,
    const u16* __restrict__ Wsign, const float* __restrict__ alpha,
    const float* __restrict__ bias, float* __restrict__ Y) {
    __shared__ u16 Alds[BM * BK];  // [128][64] linear (global_load_lds needs linear dest)
    __shared__ u16 Blds[BN * BK];

    const int tid = threadIdx.x;
    const int n0 = blockIdx.x * BN;   // 32 column blocks (fastest -> share A panel)
    const int m0 = blockIdx.y * BM;   // 128 row blocks

    const int wave = tid >> 6, lane = tid & 63;
    const int wm = wave >> 1, wn = wave & 1;        // 2x2 waves, 64x64 each
    const int lrow = lane & 15;                     // frag row (A) / col (B,D)
    const int lk8 = (lane >> 4) * 8;                // frag k-offset

    f32x4 acc[4][4];
#pragma unroll
    for (int i = 0; i < 4; ++i)
#pragma unroll
        for (int j = 0; j < 4; ++j) acc[i][j] = (f32x4){0.f, 0.f, 0.f, 0.f};

    for (int kt = 0; kt < IN_F; kt += BK) {
        // ---- stage B tile (128x64 bf16 = 16KB): 4 x global_load_lds_dwordx4 ----
#pragma unroll
        for (int j = 0; j < 4; ++j) {
            const int idx = j * 256 + tid;
            const int row = idx >> 3, c8 = idx & 7;
            gload_lds16(Wsign + (size_t)(n0 + row) * IN_F + kt + c8 * 8,
                        &Blds[idx * 8]);
        }
        // ---- stage A tile ----
        if constexpr (A_FROM_F32) {
#pragma unroll
            for (int j = 0; j < 4; ++j) {
                const int idx = j * 256 + tid;
                const int row = idx >> 3, c8 = idx & 7;
                const float* src = X + (size_t)(m0 + row) * IN_F + kt + c8 * 8;
                float4 v0 = *reinterpret_cast<const float4*>(src);
                float4 v1 = *reinterpret_cast<const float4*>(src + 4);
                u16x8 r;
                r[0] = f2bf(v0.x); r[1] = f2bf(v0.y); r[2] = f2bf(v0.z); r[3] = f2bf(v0.w);
                r[4] = f2bf(v1.x); r[5] = f2bf(v1.y); r[6] = f2bf(v1.z); r[7] = f2bf(v1.w);
                *reinterpret_cast<u16x8*>(&Alds[idx * 8]) = r;
            }
        } else {
#pragma unroll
            for (int j = 0; j < 4; ++j) {
                const int idx = j * 256 + tid;
                const int row = idx >> 3, c8 = idx & 7;
                gload_lds16(Xbf + (size_t)(m0 + row) * IN_F + kt + c8 * 8,
                            &Alds[idx * 8]);
            }
        }
        __syncthreads();  // drains vmcnt (gload_lds) + lgkmcnt (ds_write)

        // ---- compute: 2 k-subtiles of 32, 16 frags, 32 MFMAs ----
#pragma unroll
        for (int kk = 0; kk < 2; ++kk) {
            bf16x8 af[4], bf[4];
#pragma unroll
            for (int mf = 0; mf < 4; ++mf)
                af[mf] = *reinterpret_cast<const bf16x8*>(
                    &Alds[(wm * 64 + mf * 16 + lrow) * BK + kk * 32 + lk8]);
#pragma unroll
            for (int nf = 0; nf < 4; ++nf)
                bf[nf] = *reinterpret_cast<const bf16x8*>(
                    &Blds[(wn * 64 + nf * 16 + lrow) * BK + kk * 32 + lk8]);
#pragma unroll
            for (int mf = 0; mf < 4; ++mf)
#pragma unroll
                for (int nf = 0; nf < 4; ++nf)
                    acc[mf][nf] = __builtin_amdgcn_mfma_f32_16x16x32_bf16(
                        af[mf], bf[nf], acc[mf][nf], 0, 0, 0);
        }
        __syncthreads();
    }

    // ---- epilogue: y = acc*alpha[col] + bias[col] (fp32) ----
    // C/D layout (m89-verified): col = lane&15, row = (lane>>4)*4 + reg
#pragma unroll
    for (int nf = 0; nf < 4; ++nf) {
        const int col = n0 + wn * 64 + nf * 16 + lrow;
        const float al = alpha[col], bi = bias[col];
#pragma unroll
        for (int mf = 0; mf < 4; ++mf) {
            const int rbase = m0 + wm * 64 + mf * 16 + (lane >> 4) * 4;
#pragma unroll
            for (int r = 0; r < 4; ++r)
                Y[(size_t)(rbase + r) * OUT_F + col] = acc[mf][nf][r] * al + bi;
        }
    }
}

extern "C" void kernel_launch(void* const* d_in, const int* in_sizes, int n_in,
                              void* d_out, int out_size, void* d_ws, size_t ws_size,
                              hipStream_t stream) {
    const float* X    = (const float*)d_in[0];
    const float* W    = (const float*)d_in[1];
    const float* bias = (const float*)d_in[2];
    float* Y = (float*)d_out;

    char* ws = (char*)d_ws;
    float* alpha = (float*)ws;                       // 16 KB
    u16* Wsign   = (u16*)(ws + 16384);               // 32 MB
    const size_t need_safe = 16384 + (size_t)OUT_F * IN_F * 2;
    const size_t need_fast = need_safe + (size_t)NROWS * IN_F * 2;

    prep_w_kernel<<<OUT_F, 256, 0, stream>>>(W, alpha, Wsign);

    dim3 grid(OUT_F / BN, NROWS / BM);
    if (ws_size >= need_fast) {
        u16* Xbf = (u16*)(ws + need_safe);           // 128 MB
        convx_kernel<<<(size_t)NROWS * IN_F / 8 / 256, 256, 0, stream>>>(X, Xbf);
        gemm_kernel<false><<<grid, 256, 0, stream>>>(X, Xbf, Wsign, alpha, bias, Y);
    } else {
        gemm_kernel<true><<<grid, 256, 0, stream>>>(X, nullptr, Wsign, alpha, bias, Y);
    }
}

// Round 2
// 688.707 us; speedup vs baseline: 1.2837x; 1.2837x over previous
//
#include <hip/hip_runtime.h>
#include <hip/hip_bf16.h>
#include <stdint.h>

// Problem sizes (fixed by the reference)
#define IN_F  4096
#define OUT_F 4096
#define NROWS 16384
#define NT    (IN_F / 64)   // 64 K-tiles of BK=64

typedef unsigned short u16;
typedef __bf16 bf16x8 __attribute__((ext_vector_type(8)));
typedef float  f32x4  __attribute__((ext_vector_type(4)));
typedef u16    u16x8  __attribute__((ext_vector_type(8)));

#define BAR()   asm volatile("s_barrier" ::: "memory")
#define LGKM0() asm volatile("s_waitcnt lgkmcnt(0)" ::: "memory")
#define VM6()   asm volatile("s_waitcnt vmcnt(6)" ::: "memory")
#define VM0()   asm volatile("s_waitcnt vmcnt(0)" ::: "memory")

// fp32 -> bf16, round-to-nearest-even (finite inputs only)
__device__ __forceinline__ u16 f2bf(float x) {
    union { float f; uint32_t u; } c; c.f = x;
    uint32_t u = c.u;
    return (u16)((u + 0x7FFFu + ((u >> 16) & 1u)) >> 16);
}

// async global->LDS, 16B per lane. LDS dest = wave-uniform base + lane*16.
__device__ __forceinline__ void gload_lds16(const void* g, void* l) {
    __builtin_amdgcn_global_load_lds(
        (const __attribute__((address_space(1))) void*)g,
        (__attribute__((address_space(3))) void*)l, 16, 0, 0);
}

// --- Prep 1: per-row alpha = mean(|W|) AND binarized W as bf16 {+1,-1,0}.
// swz!=0: store 16B chunks permuted within each 128B group: out chunk c8
// holds input chunk c8^(row&7)  (T2 pre-swizzled global source, m173).
__global__ void prep_w_kernel(const float* __restrict__ W,
                              float* __restrict__ alpha,
                              u16* __restrict__ S, int swz) {
    const int row = blockIdx.x;                       // 0..OUT_F-1
    const float* wr = W + (size_t)row * IN_F;
    float s = 0.f;
    for (int c = threadIdx.x; c < 512; c += 256) {    // 512 out-chunks of 8 cols
        const int g = c >> 3, c8 = c & 7;
        const int c8s = swz ? (c8 ^ (row & 7)) : c8;
        const float4* src = reinterpret_cast<const float4*>(wr + g * 64 + c8s * 8);
        float4 v0 = src[0], v1 = src[1];
        s += fabsf(v0.x) + fabsf(v0.y) + fabsf(v0.z) + fabsf(v0.w)
           + fabsf(v1.x) + fabsf(v1.y) + fabsf(v1.z) + fabsf(v1.w);
        u16x8 r;
        r[0] = v0.x > 0.f ? 0x3F80 : (v0.x < 0.f ? 0xBF80 : 0);
        r[1] = v0.y > 0.f ? 0x3F80 : (v0.y < 0.f ? 0xBF80 : 0);
        r[2] = v0.z > 0.f ? 0x3F80 : (v0.z < 0.f ? 0xBF80 : 0);
        r[3] = v0.w > 0.f ? 0x3F80 : (v0.w < 0.f ? 0xBF80 : 0);
        r[4] = v1.x > 0.f ? 0x3F80 : (v1.x < 0.f ? 0xBF80 : 0);
        r[5] = v1.y > 0.f ? 0x3F80 : (v1.y < 0.f ? 0xBF80 : 0);
        r[6] = v1.z > 0.f ? 0x3F80 : (v1.z < 0.f ? 0xBF80 : 0);
        r[7] = v1.w > 0.f ? 0x3F80 : (v1.w < 0.f ? 0xBF80 : 0);
        *reinterpret_cast<u16x8*>(S + (size_t)row * IN_F + c * 8) = r;
    }
    for (int off = 32; off > 0; off >>= 1) s += __shfl_down(s, off);
    __shared__ float red[4];
    const int wave = threadIdx.x >> 6, lane = threadIdx.x & 63;
    if (lane == 0) red[wave] = s;
    __syncthreads();
    if (threadIdx.x == 0)
        alpha[row] = (red[0] + red[1] + red[2] + red[3]) * (1.0f / IN_F);
}

// --- Prep 2: x fp32 -> bf16 (RNE), same optional chunk swizzle ---
__global__ void convx_kernel(const float* __restrict__ X, u16* __restrict__ O,
                             int swz) {
    const size_t idx = (size_t)blockIdx.x * 256 + threadIdx.x; // 16B out chunk
    const int row = (int)(idx >> 9);                 // 512 chunks per row
    const int q = (int)idx & 511;
    const int g = q >> 3, c8 = q & 7;
    const int c8s = swz ? (c8 ^ (row & 7)) : c8;
    const float4* src = reinterpret_cast<const float4*>(
        X + (size_t)row * IN_F + g * 64 + c8s * 8);
    float4 a = src[0], b = src[1];
    u16x8 r;
    r[0] = f2bf(a.x); r[1] = f2bf(a.y); r[2] = f2bf(a.z); r[3] = f2bf(a.w);
    r[4] = f2bf(b.x); r[5] = f2bf(b.y); r[6] = f2bf(b.z); r[7] = f2bf(b.w);
    reinterpret_cast<u16x8*>(O)[idx] = r;
}

// ============================================================================
// 256x256 8-phase GEMM (T1+T2+T3+T4+T5), plain-HIP port of the m201 template.
// Y[m][n] = alpha[n] * sum_k Xbf[m][k]*S[n][k] + bias[n]
// 8 waves (2M x 4N), per-wave 128x64 output, BK=64, LDS 128KiB (2 dbuf x 2
// half x [128][64] x {A,B}). Xbf/Wsign are PRE-SWIZZLED in global (chunk
// c8 ^= row&7 within 128B groups) so global_load_lds stays linear and
// ds_read applies the XOR -> bank-conflict-free.
// vmcnt ledger: stage order per K-tile tau = (B-lo,B-hi,A-lo,A-hi); stage at
// phase p targets half h(p+7); vmcnt(6) once per K-tile guarantees the next
// K-tile's 4 halves are resident; overwriting stages always land >=1 barrier
// after the last ds_read of the region (reads drain at phi0/phi2 LGKM0).
// ============================================================================
__global__ __launch_bounds__(512, 2) void gemm8_kernel(
    const u16* __restrict__ Xbf, const u16* __restrict__ Wsign,
    const float* __restrict__ alpha, const float* __restrict__ bias,
    float* __restrict__ Y) {
    __shared__ u16 lds_[65536];   // 128 KiB: A slots [0,32768), B [32768,65536)

    const int tid  = threadIdx.x;
    const int lane = tid & 63, wave = tid >> 6;
    const int wm = wave >> 2, wn = wave & 3;      // 2(M) x 4(N)
    const int lrow = lane & 15;

    // T1: bijective XCD swizzle (nwg = 1024, %8==0), m-fast within chunk
    const int wg = blockIdx.x;
    const int sz = ((wg & 7) << 7) | (wg >> 3);
    const int m0 = (sz & 63) * 256;
    const int n0 = (sz >> 6) * 256;

    // T2 swizzled ds_read k-offsets (u16 units): (k8 ^ (row&7)*8), kk=1 adds ^32
    const int q0 = (((lane >> 4) << 3)) ^ ((lrow & 7) << 3);
    const int q1 = q0 ^ 32;

    // per-dbuf fragment base pointers (include lane row offset)
    const u16* Ab0 = lds_ + (0 * 2 + wm) * 8192 + lrow * 64;
    const u16* Ab1 = lds_ + (1 * 2 + wm) * 8192 + lrow * 64;
    const u16* Bb0 = lds_ + 32768 + (0 * 2 + (wn >> 1)) * 8192 + ((wn & 1) * 64 + lrow) * 64;
    const u16* Bb1 = lds_ + 32768 + (1 * 2 + (wn >> 1)) * 8192 + ((wn & 1) * 64 + lrow) * 64;

    f32x4 acc[8][4];
#pragma unroll
    for (int i = 0; i < 8; ++i)
#pragma unroll
        for (int j = 0; j < 4; ++j) acc[i][j] = (f32x4){0.f, 0.f, 0.f, 0.f};

    // stage half-tile j (0=B-lo,1=B-hi,2=A-lo,3=A-hi) of K-tile th
    auto stage = [&](int th, int j) {
        if (th >= NT) return;
        const u16* gb; int p0; u16* ls;
        if (j < 2) { gb = Wsign; p0 = n0 + j * 128;
                     ls = lds_ + 32768 + ((th & 1) * 2 + j) * 8192; }
        else       { gb = Xbf;   p0 = m0 + (j - 2) * 128;
                     ls = lds_ + ((th & 1) * 2 + (j - 2)) * 8192; }
#pragma unroll
        for (int t2 = 0; t2 < 2; ++t2) {
            const int c = t2 * 512 + tid;
            const int row = c >> 3, c8 = c & 7;
            gload_lds16(gb + (size_t)(p0 + row) * IN_F + th * 64 + c8 * 8,
                        ls + c * 8);
        }
    };

    // one K-tile = 4 phases
    auto ktile = [&](const u16* Abase, const u16* Bbase, int tau, bool last) {
        bf16x8 a0[4][2], a1[4][2], bfr[4][2];
        // --- phi0: read A-mh0 + B-all; stage (tau+1, A-hi); MFMA mh0 x np0 ---
#pragma unroll
        for (int mm = 0; mm < 4; ++mm) {
            a0[mm][0] = *reinterpret_cast<const bf16x8*>(Abase + mm * 1024 + q0);
            a0[mm][1] = *reinterpret_cast<const bf16x8*>(Abase + mm * 1024 + q1);
        }
#pragma unroll
        for (int nn = 0; nn < 4; ++nn) {
            bfr[nn][0] = *reinterpret_cast<const bf16x8*>(Bbase + nn * 1024 + q0);
            bfr[nn][1] = *reinterpret_cast<const bf16x8*>(Bbase + nn * 1024 + q1);
        }
        stage(tau + 1, 3);
        BAR(); LGKM0();
        __builtin_amdgcn_s_setprio(1);
#pragma unroll
        for (int mm = 0; mm < 4; ++mm)
#pragma unroll
            for (int nn = 0; nn < 2; ++nn) {
                acc[mm][nn] = __builtin_amdgcn_mfma_f32_16x16x32_bf16(a0[mm][0], bfr[nn][0], acc[mm][nn], 0, 0, 0);
                acc[mm][nn] = __builtin_amdgcn_mfma_f32_16x16x32_bf16(a0[mm][1], bfr[nn][1], acc[mm][nn], 0, 0, 0);
            }
        __builtin_amdgcn_s_setprio(0);
        BAR();
        // --- phi1: read A-mh1 (no wait); stage (tau+2, B-lo); MFMA mh0 x np1 ---
#pragma unroll
        for (int mm = 0; mm < 4; ++mm) {
            a1[mm][0] = *reinterpret_cast<const bf16x8*>(Abase + (4 + mm) * 1024 + q0);
            a1[mm][1] = *reinterpret_cast<const bf16x8*>(Abase + (4 + mm) * 1024 + q1);
        }
        stage(tau + 2, 0);
        BAR();
        __builtin_amdgcn_s_setprio(1);
#pragma unroll
        for (int mm = 0; mm < 4; ++mm)
#pragma unroll
            for (int nn = 0; nn < 2; ++nn) {
                acc[mm][2 + nn] = __builtin_amdgcn_mfma_f32_16x16x32_bf16(a0[mm][0], bfr[2 + nn][0], acc[mm][2 + nn], 0, 0, 0);
                acc[mm][2 + nn] = __builtin_amdgcn_mfma_f32_16x16x32_bf16(a0[mm][1], bfr[2 + nn][1], acc[mm][2 + nn], 0, 0, 0);
            }
        __builtin_amdgcn_s_setprio(0);
        BAR();
        // --- phi2: stage (tau+2, B-hi); drain a1; MFMA mh1 x np0 ---
        stage(tau + 2, 1);
        BAR(); LGKM0();
        __builtin_amdgcn_s_setprio(1);
#pragma unroll
        for (int mm = 0; mm < 4; ++mm)
#pragma unroll
            for (int nn = 0; nn < 2; ++nn) {
                acc[4 + mm][nn] = __builtin_amdgcn_mfma_f32_16x16x32_bf16(a1[mm][0], bfr[nn][0], acc[4 + mm][nn], 0, 0, 0);
                acc[4 + mm][nn] = __builtin_amdgcn_mfma_f32_16x16x32_bf16(a1[mm][1], bfr[nn][1], acc[4 + mm][nn], 0, 0, 0);
            }
        __builtin_amdgcn_s_setprio(0);
        BAR();
        // --- phi3: stage (tau+2, A-lo); MFMA mh1 x np1; boundary vmcnt ---
        stage(tau + 2, 2);
        BAR();
        __builtin_amdgcn_s_setprio(1);
#pragma unroll
        for (int mm = 0; mm < 4; ++mm)
#pragma unroll
            for (int nn = 0; nn < 2; ++nn) {
                acc[4 + mm][2 + nn] = __builtin_amdgcn_mfma_f32_16x16x32_bf16(a1[mm][0], bfr[2 + nn][0], acc[4 + mm][2 + nn], 0, 0, 0);
                acc[4 + mm][2 + nn] = __builtin_amdgcn_mfma_f32_16x16x32_bf16(a1[mm][1], bfr[2 + nn][1], acc[4 + mm][2 + nn], 0, 0, 0);
            }
        __builtin_amdgcn_s_setprio(0);
        if (last) { VM0(); } else { VM6(); }
        BAR();
    };

    // prologue: stage K0 fully + K1's first 3 halves (7 halves, 14 loads/wave)
    stage(0, 0); stage(0, 1); stage(0, 2); stage(0, 3);
    stage(1, 0); stage(1, 1); stage(1, 2);
    VM6();   // K0's 4 halves (8 oldest loads) resident
    BAR();

    for (int it = 0; it < 32; ++it) {
        const bool last = (it == 31);
        ktile(Ab0, Bb0, 2 * it, last);
        ktile(Ab1, Bb1, 2 * it + 1, last);
    }

    // epilogue: y = acc*alpha[col] + bias[col]; C/D: col=lane&15, row=(lane>>4)*4+r
#pragma unroll
    for (int nf = 0; nf < 4; ++nf) {
        const int col = n0 + wn * 64 + nf * 16 + lrow;
        const float al = alpha[col], bi = bias[col];
#pragma unroll
        for (int mf = 0; mf < 8; ++mf) {
            const int rbase = m0 + wm * 128 + mf * 16 + ((lane >> 4) << 2);
#pragma unroll
            for (int r = 0; r < 4; ++r)
                Y[(size_t)(rbase + r) * OUT_F + col] = acc[mf][nf][r] * al + bi;
        }
    }
}

// ============================================================================
// Fallback (small workspace): round-1 128x128 kernel, A reg-staged from fp32,
// Wsign UNSWIZZLED (launches with prep swz=0). Verified correct in round 1.
// ============================================================================
__global__ __launch_bounds__(256) void gemm_fallback(
    const float* __restrict__ X, const u16* __restrict__ Wsign,
    const float* __restrict__ alpha, const float* __restrict__ bias,
    float* __restrict__ Y) {
    __shared__ u16 Alds[128 * 64];
    __shared__ u16 Blds[128 * 64];

    const int tid = threadIdx.x;
    const int n0 = blockIdx.x * 128;
    const int m0 = blockIdx.y * 128;
    const int wave = tid >> 6, lane = tid & 63;
    const int wm = wave >> 1, wn = wave & 1;
    const int lrow = lane & 15;
    const int lk8 = (lane >> 4) * 8;

    f32x4 acc[4][4];
#pragma unroll
    for (int i = 0; i < 4; ++i)
#pragma unroll
        for (int j = 0; j < 4; ++j) acc[i][j] = (f32x4){0.f, 0.f, 0.f, 0.f};

    for (int kt = 0; kt < IN_F; kt += 64) {
#pragma unroll
        for (int j = 0; j < 4; ++j) {
            const int idx = j * 256 + tid;
            const int row = idx >> 3, c8 = idx & 7;
            gload_lds16(Wsign + (size_t)(n0 + row) * IN_F + kt + c8 * 8,
                        &Blds[idx * 8]);
        }
#pragma unroll
        for (int j = 0; j < 4; ++j) {
            const int idx = j * 256 + tid;
            const int row = idx >> 3, c8 = idx & 7;
            const float* src = X + (size_t)(m0 + row) * IN_F + kt + c8 * 8;
            float4 v0 = *reinterpret_cast<const float4*>(src);
            float4 v1 = *reinterpret_cast<const float4*>(src + 4);
            u16x8 r;
            r[0] = f2bf(v0.x); r[1] = f2bf(v0.y); r[2] = f2bf(v0.z); r[3] = f2bf(v0.w);
            r[4] = f2bf(v1.x); r[5] = f2bf(v1.y); r[6] = f2bf(v1.z); r[7] = f2bf(v1.w);
            *reinterpret_cast<u16x8*>(&Alds[idx * 8]) = r;
        }
        __syncthreads();
#pragma unroll
        for (int kk = 0; kk < 2; ++kk) {
            bf16x8 af[4], bf[4];
#pragma unroll
            for (int mf = 0; mf < 4; ++mf)
                af[mf] = *reinterpret_cast<const bf16x8*>(
                    &Alds[(wm * 64 + mf * 16 + lrow) * 64 + kk * 32 + lk8]);
#pragma unroll
            for (int nf = 0; nf < 4; ++nf)
                bf[nf] = *reinterpret_cast<const bf16x8*>(
                    &Blds[(wn * 64 + nf * 16 + lrow) * 64 + kk * 32 + lk8]);
#pragma unroll
            for (int mf = 0; mf < 4; ++mf)
#pragma unroll
                for (int nf = 0; nf < 4; ++nf)
                    acc[mf][nf] = __builtin_amdgcn_mfma_f32_16x16x32_bf16(
                        af[mf], bf[nf], acc[mf][nf], 0, 0, 0);
        }
        __syncthreads();
    }
#pragma unroll
    for (int nf = 0; nf < 4; ++nf) {
        const int col = n0 + wn * 64 + nf * 16 + lrow;
        const float al = alpha[col], bi = bias[col];
#pragma unroll
        for (int mf = 0; mf < 4; ++mf) {
            const int rbase = m0 + wm * 64 + mf * 16 + (lane >> 4) * 4;
#pragma unroll
            for (int r = 0; r < 4; ++r)
                Y[(size_t)(rbase + r) * OUT_F + col] = acc[mf][nf][r] * al + bi;
        }
    }
}

extern "C" void kernel_launch(void* const* d_in, const int* in_sizes, int n_in,
                              void* d_out, int out_size, void* d_ws, size_t ws_size,
                              hipStream_t stream) {
    const float* X    = (const float*)d_in[0];
    const float* W    = (const float*)d_in[1];
    const float* bias = (const float*)d_in[2];
    float* Y = (float*)d_out;

    char* ws = (char*)d_ws;
    float* alpha = (float*)ws;                       // 16 KB
    u16* Wsign   = (u16*)(ws + 16384);               // 32 MB
    const size_t need_safe = 16384 + (size_t)OUT_F * IN_F * 2;
    const size_t need_fast = need_safe + (size_t)NROWS * IN_F * 2;

    if (ws_size >= need_fast) {
        u16* Xbf = (u16*)(ws + need_safe);           // 128 MB
        prep_w_kernel<<<OUT_F, 256, 0, stream>>>(W, alpha, Wsign, 1);
        convx_kernel<<<(size_t)NROWS * IN_F / 8 / 256, 256, 0, stream>>>(X, Xbf, 1);
        gemm8_kernel<<<dim3(1024), 512, 0, stream>>>(Xbf, Wsign, alpha, bias, Y);
    } else {
        prep_w_kernel<<<OUT_F, 256, 0, stream>>>(W, alpha, Wsign, 0);
        dim3 grid(OUT_F / 128, NROWS / 128);
        gemm_fallback<<<grid, 256, 0, stream>>>(X, Wsign, alpha, bias, Y);
    }
}

// Round 3
// 620.451 us; speedup vs baseline: 1.4249x; 1.1100x over previous
//
#include <hip/hip_runtime.h>
#include <hip/hip_bf16.h>
#include <stdint.h>

// Problem sizes (fixed by the reference)
#define IN_F  4096
#define OUT_F 4096
#define NROWS 16384
#define NT    (IN_F / 64)   // 64 K-tiles of BK=64

typedef unsigned short u16;
typedef __bf16 bf16x8 __attribute__((ext_vector_type(8)));
typedef float  f32x4  __attribute__((ext_vector_type(4)));
typedef u16    u16x8  __attribute__((ext_vector_type(8)));

#define BAR()   asm volatile("s_barrier" ::: "memory")
#define LGKM0() asm volatile("s_waitcnt lgkmcnt(0)" ::: "memory")
#define VM6()   asm volatile("s_waitcnt vmcnt(6)" ::: "memory")
#define VM0()   asm volatile("s_waitcnt vmcnt(0)" ::: "memory")

// fp32 -> bf16, round-to-nearest-even (finite inputs only)
__device__ __forceinline__ u16 f2bf(float x) {
    union { float f; uint32_t u; } c; c.f = x;
    uint32_t u = c.u;
    return (u16)((u + 0x7FFFu + ((u >> 16) & 1u)) >> 16);
}

// async global->LDS, 16B per lane. LDS dest = wave-uniform base + lane*16.
__device__ __forceinline__ void gload_lds16(const void* g, void* l) {
    __builtin_amdgcn_global_load_lds(
        (const __attribute__((address_space(1))) void*)g,
        (__attribute__((address_space(3))) void*)l, 16, 0, 0);
}

__device__ __forceinline__ u16 sgn_bf16(float v) {
    return v > 0.f ? 0x3F80 : (v < 0.f ? 0xBF80 : 0);
}

// --- Prep 1: per-row alpha = mean(|W|) AND binarized W as bf16 {+1,-1,0}.
// swz!=0: store 16B chunks permuted within each 128B group: out chunk c8
// holds input chunk c8^(row&7)  (T2 pre-swizzled global source, m173).
// W is read NONTEMPORAL (read-once fp32; keep L3 for Wsign/Xbf).
__global__ void prep_w_kernel(const float* __restrict__ W,
                              float* __restrict__ alpha,
                              u16* __restrict__ S, int swz) {
    const int row = blockIdx.x;                       // 0..OUT_F-1
    const float* wr = W + (size_t)row * IN_F;
    float s = 0.f;
    for (int c = threadIdx.x; c < 512; c += 256) {    // 512 out-chunks of 8 cols
        const int g = c >> 3, c8 = c & 7;
        const int c8s = swz ? (c8 ^ (row & 7)) : c8;
        const f32x4* src = reinterpret_cast<const f32x4*>(wr + g * 64 + c8s * 8);
        f32x4 v0 = __builtin_nontemporal_load(src);
        f32x4 v1 = __builtin_nontemporal_load(src + 1);
        s += fabsf(v0[0]) + fabsf(v0[1]) + fabsf(v0[2]) + fabsf(v0[3])
           + fabsf(v1[0]) + fabsf(v1[1]) + fabsf(v1[2]) + fabsf(v1[3]);
        u16x8 r;
        r[0] = sgn_bf16(v0[0]); r[1] = sgn_bf16(v0[1]);
        r[2] = sgn_bf16(v0[2]); r[3] = sgn_bf16(v0[3]);
        r[4] = sgn_bf16(v1[0]); r[5] = sgn_bf16(v1[1]);
        r[6] = sgn_bf16(v1[2]); r[7] = sgn_bf16(v1[3]);
        *reinterpret_cast<u16x8*>(S + (size_t)row * IN_F + c * 8) = r;  // cached (read by gemm)
    }
    for (int off = 32; off > 0; off >>= 1) s += __shfl_down(s, off);
    __shared__ float red[4];
    const int wave = threadIdx.x >> 6, lane = threadIdx.x & 63;
    if (lane == 0) red[wave] = s;
    __syncthreads();
    if (threadIdx.x == 0)
        alpha[row] = (red[0] + red[1] + red[2] + red[3]) * (1.0f / IN_F);
}

// --- Prep 2: x fp32 -> bf16 (RNE), same optional chunk swizzle.
// X read NONTEMPORAL (read-once); Xbf stores cached (read by gemm). ---
__global__ void convx_kernel(const float* __restrict__ X, u16* __restrict__ O,
                             int swz) {
    const size_t idx = (size_t)blockIdx.x * 256 + threadIdx.x; // 16B out chunk
    const int row = (int)(idx >> 9);                 // 512 chunks per row
    const int q = (int)idx & 511;
    const int g = q >> 3, c8 = q & 7;
    const int c8s = swz ? (c8 ^ (row & 7)) : c8;
    const f32x4* src = reinterpret_cast<const f32x4*>(
        X + (size_t)row * IN_F + g * 64 + c8s * 8);
    f32x4 a = __builtin_nontemporal_load(src);
    f32x4 b = __builtin_nontemporal_load(src + 1);
    u16x8 r;
    r[0] = f2bf(a[0]); r[1] = f2bf(a[1]); r[2] = f2bf(a[2]); r[3] = f2bf(a[3]);
    r[4] = f2bf(b[0]); r[5] = f2bf(b[1]); r[6] = f2bf(b[2]); r[7] = f2bf(b[3]);
    reinterpret_cast<u16x8*>(O)[idx] = r;
}

// ============================================================================
// 256x256 8-phase GEMM (T1+T2+T3+T4+T5), plain-HIP port of the m201 template.
// Y[m][n] = alpha[n] * sum_k Xbf[m][k]*S[n][k] + bias[n]
// 8 waves (2M x 4N), per-wave 128x64 output, BK=64, LDS 128KiB (2 dbuf x 2
// half x [128][64] x {A,B}). Xbf/Wsign are PRE-SWIZZLED in global (chunk
// c8 ^= row&7 within 128B groups) so global_load_lds stays linear and
// ds_read applies the XOR -> bank-conflict-free (verified: 0 conflicts r2).
// Y is stored NONTEMPORAL: the 256MB write stream was evicting the 160MB
// A+B working set from the 256MB L3 (r2: FETCH=1.17GB vs 160MB compulsory).
// vmcnt ledger: stage order per K-tile tau = (B-lo,B-hi,A-lo,A-hi); stage at
// phase p targets half h(p+7); vmcnt(6) once per K-tile; overwriting stages
// always land >=1 barrier after the last ds_read of the region.
// ============================================================================
__global__ __launch_bounds__(512, 2) void gemm8_kernel(
    const u16* __restrict__ Xbf, const u16* __restrict__ Wsign,
    const float* __restrict__ alpha, const float* __restrict__ bias,
    float* __restrict__ Y) {
    __shared__ u16 lds_[65536];   // 128 KiB: A slots [0,32768), B [32768,65536)

    const int tid  = threadIdx.x;
    const int lane = tid & 63, wave = tid >> 6;
    const int wm = wave >> 2, wn = wave & 3;      // 2(M) x 4(N)
    const int lrow = lane & 15;

    // T1: bijective XCD swizzle (nwg = 1024, %8==0), m-fast within chunk
    const int wg = blockIdx.x;
    const int sz = ((wg & 7) << 7) | (wg >> 3);
    const int m0 = (sz & 63) * 256;
    const int n0 = (sz >> 6) * 256;

    // T2 swizzled ds_read k-offsets (u16 units): (k8 ^ (row&7)*8), kk=1 adds ^32
    const int q0 = (((lane >> 4) << 3)) ^ ((lrow & 7) << 3);
    const int q1 = q0 ^ 32;

    // per-dbuf fragment base pointers (include lane row offset)
    const u16* Ab0 = lds_ + (0 * 2 + wm) * 8192 + lrow * 64;
    const u16* Ab1 = lds_ + (1 * 2 + wm) * 8192 + lrow * 64;
    const u16* Bb0 = lds_ + 32768 + (0 * 2 + (wn >> 1)) * 8192 + ((wn & 1) * 64 + lrow) * 64;
    const u16* Bb1 = lds_ + 32768 + (1 * 2 + (wn >> 1)) * 8192 + ((wn & 1) * 64 + lrow) * 64;

    f32x4 acc[8][4];
#pragma unroll
    for (int i = 0; i < 8; ++i)
#pragma unroll
        for (int j = 0; j < 4; ++j) acc[i][j] = (f32x4){0.f, 0.f, 0.f, 0.f};

    // stage half-tile j (0=B-lo,1=B-hi,2=A-lo,3=A-hi) of K-tile th
    auto stage = [&](int th, int j) {
        if (th >= NT) return;
        const u16* gb; int p0; u16* ls;
        if (j < 2) { gb = Wsign; p0 = n0 + j * 128;
                     ls = lds_ + 32768 + ((th & 1) * 2 + j) * 8192; }
        else       { gb = Xbf;   p0 = m0 + (j - 2) * 128;
                     ls = lds_ + ((th & 1) * 2 + (j - 2)) * 8192; }
#pragma unroll
        for (int t2 = 0; t2 < 2; ++t2) {
            const int c = t2 * 512 + tid;
            const int row = c >> 3, c8 = c & 7;
            gload_lds16(gb + (size_t)(p0 + row) * IN_F + th * 64 + c8 * 8,
                        ls + c * 8);
        }
    };

    // one K-tile = 4 phases
    auto ktile = [&](const u16* Abase, const u16* Bbase, int tau, bool last) {
        bf16x8 a0[4][2], a1[4][2], bfr[4][2];
        // --- phi0: read A-mh0 + B-all; stage (tau+1, A-hi); MFMA mh0 x np0 ---
#pragma unroll
        for (int mm = 0; mm < 4; ++mm) {
            a0[mm][0] = *reinterpret_cast<const bf16x8*>(Abase + mm * 1024 + q0);
            a0[mm][1] = *reinterpret_cast<const bf16x8*>(Abase + mm * 1024 + q1);
        }
#pragma unroll
        for (int nn = 0; nn < 4; ++nn) {
            bfr[nn][0] = *reinterpret_cast<const bf16x8*>(Bbase + nn * 1024 + q0);
            bfr[nn][1] = *reinterpret_cast<const bf16x8*>(Bbase + nn * 1024 + q1);
        }
        stage(tau + 1, 3);
        BAR(); LGKM0();
        __builtin_amdgcn_s_setprio(1);
#pragma unroll
        for (int mm = 0; mm < 4; ++mm)
#pragma unroll
            for (int nn = 0; nn < 2; ++nn) {
                acc[mm][nn] = __builtin_amdgcn_mfma_f32_16x16x32_bf16(a0[mm][0], bfr[nn][0], acc[mm][nn], 0, 0, 0);
                acc[mm][nn] = __builtin_amdgcn_mfma_f32_16x16x32_bf16(a0[mm][1], bfr[nn][1], acc[mm][nn], 0, 0, 0);
            }
        __builtin_amdgcn_s_setprio(0);
        BAR();
        // --- phi1: read A-mh1 (no wait); stage (tau+2, B-lo); MFMA mh0 x np1 ---
#pragma unroll
        for (int mm = 0; mm < 4; ++mm) {
            a1[mm][0] = *reinterpret_cast<const bf16x8*>(Abase + (4 + mm) * 1024 + q0);
            a1[mm][1] = *reinterpret_cast<const bf16x8*>(Abase + (4 + mm) * 1024 + q1);
        }
        stage(tau + 2, 0);
        BAR();
        __builtin_amdgcn_s_setprio(1);
#pragma unroll
        for (int mm = 0; mm < 4; ++mm)
#pragma unroll
            for (int nn = 0; nn < 2; ++nn) {
                acc[mm][2 + nn] = __builtin_amdgcn_mfma_f32_16x16x32_bf16(a0[mm][0], bfr[2 + nn][0], acc[mm][2 + nn], 0, 0, 0);
                acc[mm][2 + nn] = __builtin_amdgcn_mfma_f32_16x16x32_bf16(a0[mm][1], bfr[2 + nn][1], acc[mm][2 + nn], 0, 0, 0);
            }
        __builtin_amdgcn_s_setprio(0);
        BAR();
        // --- phi2: stage (tau+2, B-hi); drain a1; MFMA mh1 x np0 ---
        stage(tau + 2, 1);
        BAR(); LGKM0();
        __builtin_amdgcn_s_setprio(1);
#pragma unroll
        for (int mm = 0; mm < 4; ++mm)
#pragma unroll
            for (int nn = 0; nn < 2; ++nn) {
                acc[4 + mm][nn] = __builtin_amdgcn_mfma_f32_16x16x32_bf16(a1[mm][0], bfr[nn][0], acc[4 + mm][nn], 0, 0, 0);
                acc[4 + mm][nn] = __builtin_amdgcn_mfma_f32_16x16x32_bf16(a1[mm][1], bfr[nn][1], acc[4 + mm][nn], 0, 0, 0);
            }
        __builtin_amdgcn_s_setprio(0);
        BAR();
        // --- phi3: stage (tau+2, A-lo); MFMA mh1 x np1; boundary vmcnt ---
        stage(tau + 2, 2);
        BAR();
        __builtin_amdgcn_s_setprio(1);
#pragma unroll
        for (int mm = 0; mm < 4; ++mm)
#pragma unroll
            for (int nn = 0; nn < 2; ++nn) {
                acc[4 + mm][2 + nn] = __builtin_amdgcn_mfma_f32_16x16x32_bf16(a1[mm][0], bfr[2 + nn][0], acc[4 + mm][2 + nn], 0, 0, 0);
                acc[4 + mm][2 + nn] = __builtin_amdgcn_mfma_f32_16x16x32_bf16(a1[mm][1], bfr[2 + nn][1], acc[4 + mm][2 + nn], 0, 0, 0);
            }
        __builtin_amdgcn_s_setprio(0);
        if (last) { VM0(); } else { VM6(); }
        BAR();
    };

    // prologue: stage K0 fully + K1's first 3 halves (7 halves, 14 loads/wave)
    stage(0, 0); stage(0, 1); stage(0, 2); stage(0, 3);
    stage(1, 0); stage(1, 1); stage(1, 2);
    VM6();   // K0's 4 halves (8 oldest loads) resident
    BAR();

    for (int it = 0; it < 32; ++it) {
        const bool last = (it == 31);
        ktile(Ab0, Bb0, 2 * it, last);
        ktile(Ab1, Bb1, 2 * it + 1, last);
    }

    // epilogue: y = acc*alpha[col] + bias[col]; C/D: col=lane&15, row=(lane>>4)*4+r
    // NONTEMPORAL stores: Y is write-once, keep it out of L3.
#pragma unroll
    for (int nf = 0; nf < 4; ++nf) {
        const int col = n0 + wn * 64 + nf * 16 + lrow;
        const float al = alpha[col], bi = bias[col];
#pragma unroll
        for (int mf = 0; mf < 8; ++mf) {
            const int rbase = m0 + wm * 128 + mf * 16 + ((lane >> 4) << 2);
#pragma unroll
            for (int r = 0; r < 4; ++r)
                __builtin_nontemporal_store(acc[mf][nf][r] * al + bi,
                    &Y[(size_t)(rbase + r) * OUT_F + col]);
        }
    }
}

// ============================================================================
// Fallback (small workspace): round-1 128x128 kernel, A reg-staged from fp32,
// Wsign UNSWIZZLED (launches with prep swz=0). Verified correct in round 1.
// ============================================================================
__global__ __launch_bounds__(256) void gemm_fallback(
    const float* __restrict__ X, const u16* __restrict__ Wsign,
    const float* __restrict__ alpha, const float* __restrict__ bias,
    float* __restrict__ Y) {
    __shared__ u16 Alds[128 * 64];
    __shared__ u16 Blds[128 * 64];

    const int tid = threadIdx.x;
    const int n0 = blockIdx.x * 128;
    const int m0 = blockIdx.y * 128;
    const int wave = tid >> 6, lane = tid & 63;
    const int wm = wave >> 1, wn = wave & 1;
    const int lrow = lane & 15;
    const int lk8 = (lane >> 4) * 8;

    f32x4 acc[4][4];
#pragma unroll
    for (int i = 0; i < 4; ++i)
#pragma unroll
        for (int j = 0; j < 4; ++j) acc[i][j] = (f32x4){0.f, 0.f, 0.f, 0.f};

    for (int kt = 0; kt < IN_F; kt += 64) {
#pragma unroll
        for (int j = 0; j < 4; ++j) {
            const int idx = j * 256 + tid;
            const int row = idx >> 3, c8 = idx & 7;
            gload_lds16(Wsign + (size_t)(n0 + row) * IN_F + kt + c8 * 8,
                        &Blds[idx * 8]);
        }
#pragma unroll
        for (int j = 0; j < 4; ++j) {
            const int idx = j * 256 + tid;
            const int row = idx >> 3, c8 = idx & 7;
            const float* src = X + (size_t)(m0 + row) * IN_F + kt + c8 * 8;
            float4 v0 = *reinterpret_cast<const float4*>(src);
            float4 v1 = *reinterpret_cast<const float4*>(src + 4);
            u16x8 r;
            r[0] = f2bf(v0.x); r[1] = f2bf(v0.y); r[2] = f2bf(v0.z); r[3] = f2bf(v0.w);
            r[4] = f2bf(v1.x); r[5] = f2bf(v1.y); r[6] = f2bf(v1.z); r[7] = f2bf(v1.w);
            *reinterpret_cast<u16x8*>(&Alds[idx * 8]) = r;
        }
        __syncthreads();
#pragma unroll
        for (int kk = 0; kk < 2; ++kk) {
            bf16x8 af[4], bf[4];
#pragma unroll
            for (int mf = 0; mf < 4; ++mf)
                af[mf] = *reinterpret_cast<const bf16x8*>(
                    &Alds[(wm * 64 + mf * 16 + lrow) * 64 + kk * 32 + lk8]);
#pragma unroll
            for (int nf = 0; nf < 4; ++nf)
                bf[nf] = *reinterpret_cast<const bf16x8*>(
                    &Blds[(wn * 64 + nf * 16 + lrow) * 64 + kk * 32 + lk8]);
#pragma unroll
            for (int mf = 0; mf < 4; ++mf)
#pragma unroll
                for (int nf = 0; nf < 4; ++nf)
                    acc[mf][nf] = __builtin_amdgcn_mfma_f32_16x16x32_bf16(
                        af[mf], bf[nf], acc[mf][nf], 0, 0, 0);
        }
        __syncthreads();
    }
#pragma unroll
    for (int nf = 0; nf < 4; ++nf) {
        const int col = n0 + wn * 64 + nf * 16 + lrow;
        const float al = alpha[col], bi = bias[col];
#pragma unroll
        for (int mf = 0; mf < 4; ++mf) {
            const int rbase = m0 + wm * 64 + mf * 16 + (lane >> 4) * 4;
#pragma unroll
            for (int r = 0; r < 4; ++r)
                __builtin_nontemporal_store(acc[mf][nf][r] * al + bi,
                    &Y[(size_t)(rbase + r) * OUT_F + col]);
        }
    }
}

extern "C" void kernel_launch(void* const* d_in, const int* in_sizes, int n_in,
                              void* d_out, int out_size, void* d_ws, size_t ws_size,
                              hipStream_t stream) {
    const float* X    = (const float*)d_in[0];
    const float* W    = (const float*)d_in[1];
    const float* bias = (const float*)d_in[2];
    float* Y = (float*)d_out;

    char* ws = (char*)d_ws;
    float* alpha = (float*)ws;                       // 16 KB
    u16* Wsign   = (u16*)(ws + 16384);               // 32 MB
    const size_t need_safe = 16384 + (size_t)OUT_F * IN_F * 2;
    const size_t need_fast = need_safe + (size_t)NROWS * IN_F * 2;

    if (ws_size >= need_fast) {
        u16* Xbf = (u16*)(ws + need_safe);           // 128 MB
        prep_w_kernel<<<OUT_F, 256, 0, stream>>>(W, alpha, Wsign, 1);
        convx_kernel<<<(size_t)NROWS * IN_F / 8 / 256, 256, 0, stream>>>(X, Xbf, 1);
        gemm8_kernel<<<dim3(1024), 512, 0, stream>>>(Xbf, Wsign, alpha, bias, Y);
    } else {
        prep_w_kernel<<<OUT_F, 256, 0, stream>>>(W, alpha, Wsign, 0);
        dim3 grid(OUT_F / 128, NROWS / 128);
        gemm_fallback<<<grid, 256, 0, stream>>>(X, Wsign, alpha, bias, Y);
    }
}